// Round 1
// baseline (8808.797 us; speedup 1.0000x reference)
//
#include <hip/hip_runtime.h>
#include <hip/hip_cooperative_groups.h>
#include <math.h>

namespace cg = cooperative_groups;

#define S_LEN 100
#define HID   256
#define EMB   256
#define BATCH 64
#define NCAT  18

// ws layout (floats):
//   h0buf: [2 buf][2 lstm][256 k][64 b]  at 0      (65536 floats)
//   h1buf: same                          at 65536  (65536 floats)
// total 131072 floats = 512 KB

struct Params {
  const int* ivu; const int* ivo;
  const float* lro; const float* lru;
  const float* VE;
  const float* W[4][2];   // [inst][part]; inst: bit0=lstm, bit1=layer; part0=Wih, part1=Whh
  const float* b0[4]; const float* b1[4];
  const float* roW; const float* rob;
  const float* ruW; const float* rub;
  float* ws; float* out;
};

__global__ __launch_bounds__(512, 2) void lstm_all(Params P) {
  __shared__ union {
    struct { float gate[8][16][64]; float c[4][64]; } l;   // 33 KB
    struct { float enc[64 * 256]; float dec[64 * NCAT]; float kl[64]; } h; // 69 KB
  } sh;

  cg::grid_group grid = cg::this_grid();
  const int tid  = threadIdx.x;
  const int lane = tid & 63;
  const int wave = __builtin_amdgcn_readfirstlane((int)(threadIdx.x >> 6)); // force SGPR
  const int blk  = blockIdx.x;
  const int inst = blk >> 6;        // 0..3
  const int wg   = blk & 63;        // 0..63
  const int m0   = wg << 2;         // this WG owns m = m0..m0+3
  const int lstm = inst & 1;
  const int layer = inst >> 1;

  // zero the h state buffers: exactly one float per thread (256*512 == 131072)
  P.ws[blk * 512 + tid] = 0.f;
  if (tid < 256) sh.l.c[tid >> 6][tid & 63] = 0.f;

  const float* __restrict__ W0 = P.W[inst][0];
  const float* __restrict__ W1 = P.W[inst][1];
  const int part = wave >> 2;          // 0: input-part, 1: hidden-part
  const int kloc = (wave & 3) << 6;    // 0,64,128,192 within the part
  const float* __restrict__ Wp = part ? W1 : W0;
  const int* __restrict__ idxp = lstm ? P.ivo : P.ivu;

  float* h0b = P.ws;            // [buf][lstm][k][b]
  float* h1b = P.ws + 65536;

  grid.sync();

  for (int t = 0; t <= S_LEN; ++t) {
    const bool active = (layer == 0) ? (t < S_LEN) : (t >= 1);
    if (active) {
      const int cur = t & 1, prv = (t + 1) & 1;
      float acc[16];
      #pragma unroll
      for (int jj = 0; jj < 16; ++jj) acc[jj] = 0.f;

      if (layer == 0 && part == 0) {
        // gather path: emb_t[k][b] = VE[idx[b][t]][k]; per-lane contiguous rows
        const int row = idxp[lane * S_LEN + t];
        const float* __restrict__ vr = P.VE + (size_t)row * EMB + kloc;
        #pragma unroll
        for (int kk = 0; kk < 64; kk += 8) {
          float4 a0 = *(const float4*)(vr + kk);
          float4 a1 = *(const float4*)(vr + kk + 4);
          float x[8] = {a0.x, a0.y, a0.z, a0.w, a1.x, a1.y, a1.z, a1.w};
          #pragma unroll
          for (int jj = 0; jj < 16; ++jj) {
            const float* __restrict__ wr =
                Wp + (size_t)((jj >> 2) * HID + m0 + (jj & 3)) * 256 + kloc + kk;
            #pragma unroll
            for (int i = 0; i < 8; ++i) acc[jj] = fmaf(x[i], wr[i], acc[jj]);
          }
        }
      } else {
        // transposed-buffer path: in[k][b], coalesced per k
        const float* inT;
        if (layer == 0)      inT = h0b + prv * 32768 + lstm * 16384;          // h0_{t-1}
        else if (part == 0)  inT = h0b + prv * 32768 + lstm * 16384;          // y0_{t-1}
        else                 inT = h1b + cur * 32768 + lstm * 16384;          // h1_{t-2}
        const float* __restrict__ ip = inT + kloc * 64 + lane;
        #pragma unroll
        for (int kk = 0; kk < 64; kk += 8) {
          float x[8];
          #pragma unroll
          for (int i = 0; i < 8; ++i) x[i] = ip[(kk + i) * 64];
          #pragma unroll
          for (int jj = 0; jj < 16; ++jj) {
            const float* __restrict__ wr =
                Wp + (size_t)((jj >> 2) * HID + m0 + (jj & 3)) * 256 + kloc + kk;
            #pragma unroll
            for (int i = 0; i < 8; ++i) acc[jj] = fmaf(x[i], wr[i], acc[jj]);
          }
        }
      }

      #pragma unroll
      for (int jj = 0; jj < 16; ++jj) sh.l.gate[wave][jj][lane] = acc[jj];
      __syncthreads();

      if (tid < 256) {
        const int mi = tid >> 6, b = tid & 63, m = m0 + mi;
        float g4[4];
        #pragma unroll
        for (int g = 0; g < 4; ++g) {
          float s = P.b0[inst][g * HID + m] + P.b1[inst][g * HID + m];
          #pragma unroll
          for (int wv = 0; wv < 8; ++wv) s += sh.l.gate[wv][g * 4 + mi][b];
          g4[g] = s;
        }
        const float ig = 1.f / (1.f + __expf(-g4[0]));
        const float fg = 1.f / (1.f + __expf(-g4[1]));
        const float gg = tanhf(g4[2]);
        const float og = 1.f / (1.f + __expf(-g4[3]));
        const float c  = fg * sh.l.c[mi][b] + ig * gg;
        sh.l.c[mi][b] = c;
        const float hv = og * tanhf(c);
        // layer0 writes h0buf[t&1]; layer1 (step s=t-1) writes h1buf[s&1]=(t+1)&1
        float* hout = (layer == 0 ? h0b + (t & 1) * 32768
                                  : h1b + ((t + 1) & 1) * 32768) + lstm * 16384;
        hout[m * 64 + b] = hv;
      }
    }
    __threadfence();
    grid.sync();
  }

  // ---- head: WG0 only ----
  if (blk == 0) {
    const float* __restrict__ hvu = h1b + 32768;           // h1 final (buf 1), lstm vu
    const float* __restrict__ hvo = h1b + 32768 + 16384;   // lstm vo
    for (int i = tid; i < 64 * 256; i += 512) {
      const int b = i >> 8, m = i & 255;
      float s = P.rob[m];
      for (int j = 0; j < NCAT; ++j) s = fmaf(P.lro[b * NCAT + j], P.roW[m * NCAT + j], s);
      sh.h.enc[i] = fmaxf(s, 0.f);
    }
    __syncthreads();
    for (int i = tid; i < 64 * NCAT; i += 512) {
      const int b = i / NCAT, n = i - b * NCAT;
      const float* __restrict__ wr = P.ruW + n * 768;
      float s = P.rub[n];
      for (int k = 0; k < 256; ++k) s = fmaf(hvu[k * 64 + b], wr[k], s);
      for (int k = 0; k < 256; ++k) s = fmaf(hvo[k * 64 + b], wr[256 + k], s);
      const float* __restrict__ eb = sh.h.enc + b * 256;
      for (int k = 0; k < 256; ++k) s = fmaf(eb[k], wr[512 + k], s);
      sh.h.dec[i] = s;
    }
    __syncthreads();
    if (tid < 64) {
      const int b = tid;
      const float* db = sh.h.dec + b * NCAT;
      float M = db[0];
      for (int j = 1; j < NCAT; ++j) M = fmaxf(M, db[j]);
      float Ssum = 0.f;
      for (int j = 0; j < NCAT; ++j) Ssum += expf(db[j] - M);
      const float lse = M + logf(Ssum);
      float neg = 0.f, kl = 0.f;
      for (int j = 0; j < NCAT; ++j) {
        const float lp = db[j] - lse;
        const float q  = P.lru[b * NCAT + j];
        neg -= q * lp;
        kl  += q * (logf(q) - lp);
      }
      P.out[b] = neg;
      sh.h.kl[b] = kl * 1.4426950408889634f;  // ln -> log2
    }
    __syncthreads();
    if (tid == 0) {
      float s = 0.f;
      for (int b = 0; b < 64; ++b) s += sh.h.kl[b];
      P.out[64] = s * (1.f / 64.f);
    }
  }
}

extern "C" void kernel_launch(void* const* d_in, const int* in_sizes, int n_in,
                              void* d_out, int out_size, void* d_ws, size_t ws_size,
                              hipStream_t stream) {
  Params P;
  P.ivu = (const int*)d_in[0];
  P.ivo = (const int*)d_in[1];
  P.lro = (const float*)d_in[2];
  // setup_inputs dict order: video_embeddings at 3, label_ru at 4 — verify by size.
  if (in_sizes[3] >= in_sizes[4]) { P.VE = (const float*)d_in[3]; P.lru = (const float*)d_in[4]; }
  else                            { P.VE = (const float*)d_in[4]; P.lru = (const float*)d_in[3]; }
  // inst: 0 = vu-L0, 1 = vo-L0, 2 = vu-L1, 3 = vo-L1
  P.W[0][0] = (const float*)d_in[5];  P.W[0][1] = (const float*)d_in[6];
  P.b0[0]   = (const float*)d_in[7];  P.b1[0]   = (const float*)d_in[8];
  P.W[2][0] = (const float*)d_in[9];  P.W[2][1] = (const float*)d_in[10];
  P.b0[2]   = (const float*)d_in[11]; P.b1[2]   = (const float*)d_in[12];
  P.W[1][0] = (const float*)d_in[13]; P.W[1][1] = (const float*)d_in[14];
  P.b0[1]   = (const float*)d_in[15]; P.b1[1]   = (const float*)d_in[16];
  P.W[3][0] = (const float*)d_in[17]; P.W[3][1] = (const float*)d_in[18];
  P.b0[3]   = (const float*)d_in[19]; P.b1[3]   = (const float*)d_in[20];
  P.roW = (const float*)d_in[21]; P.rob = (const float*)d_in[22];
  P.ruW = (const float*)d_in[23]; P.rub = (const float*)d_in[24];
  P.ws  = (float*)d_ws;
  P.out = (float*)d_out;
  void* args[] = { &P };
  hipLaunchCooperativeKernel((void*)lstm_all, dim3(256), dim3(512), args, 0, stream);
}

// Round 2
// 3561.872 us; speedup vs baseline: 2.4731x; 2.4731x over previous
//
#include <hip/hip_runtime.h>
#include <math.h>

#define S_LEN 100
#define HID   256
#define EMB   256
#define NCAT  18

// ws layout (floats):
//   h0buf: [2 buf][2 lstm][256 k][64 b]  at 0      (65536 floats)
//   h1buf: same                          at 65536  (65536 floats)
//   barrier words (unsigned) at float-offset 131072: 128 words
//     group g (g=lstm): cnt = cw[g*64], flag = cw[g*64+16]

struct Params {
  const int* ivu; const int* ivo;
  const float* lro; const float* lru;
  const float* VE;
  const float* W[4][2];   // [inst][part]; inst: bit0=lstm, bit1=layer; part0=Wih, part1=Whh
  const float* b0[4]; const float* b1[4];
  const float* roW; const float* rob;
  const float* ruW; const float* rub;
  float* ws; float* out;
};

__global__ void init_counters(unsigned* p) { p[threadIdx.x] = 0u; }

// monotonic-epoch barrier over 128 blocks; thread 0 arrives/spins, rest wait at s_barrier
__device__ __forceinline__ void group_barrier(unsigned* cnt, unsigned* flag, unsigned epoch) {
  __syncthreads();
  if (threadIdx.x == 0) {
    __threadfence();  // release: drain + make this WG's global stores device-visible
    unsigned old = __hip_atomic_fetch_add(cnt, 1u, __ATOMIC_RELAXED, __HIP_MEMORY_SCOPE_AGENT);
    if (old == epoch * 128u - 1u) {
      __hip_atomic_store(flag, epoch, __ATOMIC_RELEASE, __HIP_MEMORY_SCOPE_AGENT);
    } else {
      while (__hip_atomic_load(flag, __ATOMIC_RELAXED, __HIP_MEMORY_SCOPE_AGENT) < epoch)
        __builtin_amdgcn_s_sleep(2);
    }
    __threadfence();  // acquire: invalidate stale cached copies before reading peers' data
  }
  __syncthreads();
}

__global__ __launch_bounds__(512, 1) void lstm_all(Params P) {
  __shared__ union {
    struct { float gate[8][16][64]; float c[4][64]; } l;   // 33 KB
    struct { float enc[64 * 256]; float dec[64 * NCAT]; float kl[64]; } h; // 69 KB
  } sh;

  const int tid  = threadIdx.x;
  const int lane = tid & 63;
  const int wave = __builtin_amdgcn_readfirstlane((int)(threadIdx.x >> 6)); // force SGPR
  const int blk  = blockIdx.x;
  const int inst = blk >> 6;        // 0..3
  const int wg   = blk & 63;        // 0..63
  const int m0   = wg << 2;         // this WG owns m = m0..m0+3
  const int lstm = inst & 1;        // barrier group id
  const int layer = inst >> 1;

  unsigned* cw   = (unsigned*)(P.ws + 131072);
  unsigned* cnt  = cw + lstm * 64;
  unsigned* flag = cnt + 16;

  // zero this group's h buffers (group-aligned so visibility stays within the group)
  {
    const int gb = (blk & 63) | ((blk >> 7) << 6);      // 0..127 within group
    const int i  = gb * 512 + tid;                      // 0..65535
    const int region = i >> 14;                         // 0..3
    const int off = i & 16383;
    const int rbase = region * 32768;                   // h0b buf0/buf1, h1b buf0/buf1
    P.ws[rbase + lstm * 16384 + off] = 0.f;
  }
  if (tid < 256) sh.l.c[tid >> 6][tid & 63] = 0.f;

  const float* __restrict__ W0 = P.W[inst][0];
  const float* __restrict__ W1 = P.W[inst][1];
  const int part = wave >> 2;          // 0: input-part, 1: hidden-part
  const int kloc = (wave & 3) << 6;    // 0,64,128,192 within the part
  const float* __restrict__ Wp = part ? W1 : W0;
  const int* __restrict__ idxp = lstm ? P.ivo : P.ivu;

  float* h0b = P.ws;            // [buf][lstm][k][b]
  float* h1b = P.ws + 65536;

  group_barrier(cnt, flag, 1u);   // zero-init visible to whole group

  for (int t = 0; t <= S_LEN; ++t) {
    const bool active = (layer == 0) ? (t < S_LEN) : (t >= 1);
    if (active) {
      const int cur = t & 1, prv = (t + 1) & 1;
      float acc[16];
      #pragma unroll
      for (int jj = 0; jj < 16; ++jj) acc[jj] = 0.f;

      if (layer == 0 && part == 0) {
        // gather path: emb_t[k][b] = VE[idx[b][t]][k]; per-lane contiguous rows
        const int row = idxp[lane * S_LEN + t];
        const float* __restrict__ vr = P.VE + (size_t)row * EMB + kloc;
        #pragma unroll
        for (int kk = 0; kk < 64; kk += 8) {
          float4 a0 = *(const float4*)(vr + kk);
          float4 a1 = *(const float4*)(vr + kk + 4);
          #pragma unroll
          for (int jj = 0; jj < 16; ++jj) {
            const float* __restrict__ wr =
                Wp + (size_t)((jj >> 2) * HID + m0 + (jj & 3)) * 256 + kloc + kk;
            float4 w0 = *(const float4*)(wr);
            float4 w1 = *(const float4*)(wr + 4);
            float s = acc[jj];
            s = fmaf(a0.x, w0.x, s); s = fmaf(a0.y, w0.y, s);
            s = fmaf(a0.z, w0.z, s); s = fmaf(a0.w, w0.w, s);
            s = fmaf(a1.x, w1.x, s); s = fmaf(a1.y, w1.y, s);
            s = fmaf(a1.z, w1.z, s); s = fmaf(a1.w, w1.w, s);
            acc[jj] = s;
          }
        }
      } else {
        // transposed-buffer path: in[k][b], coalesced per k
        const float* inT;
        if (layer == 0)      inT = h0b + prv * 32768 + lstm * 16384;          // h0_{t-1}
        else if (part == 0)  inT = h0b + prv * 32768 + lstm * 16384;          // y0_{t-1}
        else                 inT = h1b + cur * 32768 + lstm * 16384;          // h1_{t-2}
        const float* __restrict__ ip = inT + kloc * 64 + lane;
        #pragma unroll
        for (int kk = 0; kk < 64; kk += 8) {
          float x[8];
          #pragma unroll
          for (int i = 0; i < 8; ++i) x[i] = ip[(kk + i) * 64];
          #pragma unroll
          for (int jj = 0; jj < 16; ++jj) {
            const float* __restrict__ wr =
                Wp + (size_t)((jj >> 2) * HID + m0 + (jj & 3)) * 256 + kloc + kk;
            float4 w0 = *(const float4*)(wr);
            float4 w1 = *(const float4*)(wr + 4);
            float s = acc[jj];
            s = fmaf(x[0], w0.x, s); s = fmaf(x[1], w0.y, s);
            s = fmaf(x[2], w0.z, s); s = fmaf(x[3], w0.w, s);
            s = fmaf(x[4], w1.x, s); s = fmaf(x[5], w1.y, s);
            s = fmaf(x[6], w1.z, s); s = fmaf(x[7], w1.w, s);
            acc[jj] = s;
          }
        }
      }

      #pragma unroll
      for (int jj = 0; jj < 16; ++jj) sh.l.gate[wave][jj][lane] = acc[jj];
      __syncthreads();

      if (tid < 256) {
        const int mi = tid >> 6, b = tid & 63, m = m0 + mi;
        float g4[4];
        #pragma unroll
        for (int g = 0; g < 4; ++g) {
          float s = P.b0[inst][g * HID + m] + P.b1[inst][g * HID + m];
          #pragma unroll
          for (int wv = 0; wv < 8; ++wv) s += sh.l.gate[wv][g * 4 + mi][b];
          g4[g] = s;
        }
        const float ig = 1.f / (1.f + __expf(-g4[0]));
        const float fg = 1.f / (1.f + __expf(-g4[1]));
        const float gg = tanhf(g4[2]);
        const float og = 1.f / (1.f + __expf(-g4[3]));
        const float c  = fg * sh.l.c[mi][b] + ig * gg;
        sh.l.c[mi][b] = c;
        const float hv = og * tanhf(c);
        // layer0 writes h0buf[t&1]; layer1 (step s=t-1) writes h1buf[s&1]=(t+1)&1
        float* hout = (layer == 0 ? h0b + (t & 1) * 32768
                                  : h1b + ((t + 1) & 1) * 32768) + lstm * 16384;
        hout[m * 64 + b] = hv;
      }
    }
    group_barrier(cnt, flag, (unsigned)(t + 2));
  }

  // ---- head: WG0 only (vu group); must also wait for vo group's final epoch ----
  if (blk == 0) {
    if (tid == 0) {
      unsigned* flag_vo = cw + 64 + 16;
      while (__hip_atomic_load(flag_vo, __ATOMIC_RELAXED, __HIP_MEMORY_SCOPE_AGENT) < (unsigned)(S_LEN + 2))
        __builtin_amdgcn_s_sleep(2);
      __threadfence();
    }
    __syncthreads();

    const float* __restrict__ hvu = h1b + 32768;           // h1 final (buf 1), lstm vu
    const float* __restrict__ hvo = h1b + 32768 + 16384;   // lstm vo
    for (int i = tid; i < 64 * 256; i += 512) {
      const int b = i >> 8, m = i & 255;
      float s = P.rob[m];
      for (int j = 0; j < NCAT; ++j) s = fmaf(P.lro[b * NCAT + j], P.roW[m * NCAT + j], s);
      sh.h.enc[i] = fmaxf(s, 0.f);
    }
    __syncthreads();
    for (int i = tid; i < 64 * NCAT; i += 512) {
      const int b = i / NCAT, n = i - b * NCAT;
      const float* __restrict__ wr = P.ruW + n * 768;
      float s = P.rub[n];
      for (int k = 0; k < 256; ++k) s = fmaf(hvu[k * 64 + b], wr[k], s);
      for (int k = 0; k < 256; ++k) s = fmaf(hvo[k * 64 + b], wr[256 + k], s);
      const float* __restrict__ eb = sh.h.enc + b * 256;
      for (int k = 0; k < 256; ++k) s = fmaf(eb[k], wr[512 + k], s);
      sh.h.dec[i] = s;
    }
    __syncthreads();
    if (tid < 64) {
      const int b = tid;
      const float* db = sh.h.dec + b * NCAT;
      float M = db[0];
      for (int j = 1; j < NCAT; ++j) M = fmaxf(M, db[j]);
      float Ssum = 0.f;
      for (int j = 0; j < NCAT; ++j) Ssum += expf(db[j] - M);
      const float lse = M + logf(Ssum);
      float neg = 0.f, kl = 0.f;
      for (int j = 0; j < NCAT; ++j) {
        const float lp = db[j] - lse;
        const float q  = P.lru[b * NCAT + j];
        neg -= q * lp;
        kl  += q * (logf(q) - lp);
      }
      P.out[b] = neg;
      sh.h.kl[b] = kl * 1.4426950408889634f;  // ln -> log2
    }
    __syncthreads();
    if (tid == 0) {
      float s = 0.f;
      for (int b = 0; b < 64; ++b) s += sh.h.kl[b];
      P.out[64] = s * (1.f / 64.f);
    }
  }
}

extern "C" void kernel_launch(void* const* d_in, const int* in_sizes, int n_in,
                              void* d_out, int out_size, void* d_ws, size_t ws_size,
                              hipStream_t stream) {
  Params P;
  P.ivu = (const int*)d_in[0];
  P.ivo = (const int*)d_in[1];
  P.lro = (const float*)d_in[2];
  if (in_sizes[3] >= in_sizes[4]) { P.VE = (const float*)d_in[3]; P.lru = (const float*)d_in[4]; }
  else                            { P.VE = (const float*)d_in[4]; P.lru = (const float*)d_in[3]; }
  // inst: 0 = vu-L0, 1 = vo-L0, 2 = vu-L1, 3 = vo-L1
  P.W[0][0] = (const float*)d_in[5];  P.W[0][1] = (const float*)d_in[6];
  P.b0[0]   = (const float*)d_in[7];  P.b1[0]   = (const float*)d_in[8];
  P.W[2][0] = (const float*)d_in[9];  P.W[2][1] = (const float*)d_in[10];
  P.b0[2]   = (const float*)d_in[11]; P.b1[2]   = (const float*)d_in[12];
  P.W[1][0] = (const float*)d_in[13]; P.W[1][1] = (const float*)d_in[14];
  P.b0[1]   = (const float*)d_in[15]; P.b1[1]   = (const float*)d_in[16];
  P.W[3][0] = (const float*)d_in[17]; P.W[3][1] = (const float*)d_in[18];
  P.b0[3]   = (const float*)d_in[19]; P.b1[3]   = (const float*)d_in[20];
  P.roW = (const float*)d_in[21]; P.rob = (const float*)d_in[22];
  P.ruW = (const float*)d_in[23]; P.rub = (const float*)d_in[24];
  P.ws  = (float*)d_ws;
  P.out = (float*)d_out;

  unsigned* cw = (unsigned*)((float*)d_ws + 131072);
  init_counters<<<1, 128, 0, stream>>>(cw);

  void* args[] = { &P };
  hipLaunchCooperativeKernel((void*)lstm_all, dim3(256), dim3(512), args, 0, stream);
}

// Round 3
// 3474.411 us; speedup vs baseline: 2.5353x; 1.0252x over previous
//
#include <hip/hip_runtime.h>
#include <math.h>

#define S_LEN 100
#define HID   256
#define EMB   256
#define NCAT  18

// ws layout (floats):
//   h0buf: [2 buf][2 lstm][256 k][64 b]  at 0      (65536 floats)
//   h1buf: same                          at 65536  (65536 floats)
// barrier area (unsigned) at dword-offset 131072, per group g in {0,1}:
//   arr  = cw + g*4096        : 128 slots x 16 dwords (64B padded)
//   flag = cw + g*4096 + 2048 : 1 dword
// total ws = 131072 + 8192 dwords = 557 KB

struct Params {
  const int* ivu; const int* ivo;
  const float* lro; const float* lru;
  const float* VE;
  const float* W[4][2];   // [inst][part]; inst: bit0=lstm, bit1=layer; part0=Wih, part1=Whh
  const float* b0[4]; const float* b1[4];
  const float* roW; const float* rob;
  const float* ruW; const float* rub;
  float* ws; float* out;
};

__global__ void init_counters(unsigned* p) {
  p[blockIdx.x * 256 + threadIdx.x] = 0u;   // 32*256 = 8192 dwords
}

// flag-array barrier over 128 WGs: arrival = plain release store to own padded
// slot (no RMW serialization); master wave polls 128 slots, sets release flag.
__device__ __forceinline__ void group_barrier(unsigned* arr, unsigned* flag,
                                              unsigned epoch, int gb, bool master) {
  __syncthreads();
  if (threadIdx.x == 0) {
    __threadfence();  // drain this WG's global stores to device-visible point
    __hip_atomic_store(arr + gb * 16, epoch, __ATOMIC_RELEASE, __HIP_MEMORY_SCOPE_AGENT);
  }
  if (master && threadIdx.x < 64) {
    unsigned* s0 = arr + threadIdx.x * 16;
    unsigned* s1 = arr + (threadIdx.x + 64) * 16;
    for (;;) {
      unsigned a = __hip_atomic_load(s0, __ATOMIC_RELAXED, __HIP_MEMORY_SCOPE_AGENT);
      unsigned b = __hip_atomic_load(s1, __ATOMIC_RELAXED, __HIP_MEMORY_SCOPE_AGENT);
      if (__all(a >= epoch && b >= epoch)) break;
      __builtin_amdgcn_s_sleep(1);
    }
    if (threadIdx.x == 0)
      __hip_atomic_store(flag, epoch, __ATOMIC_RELEASE, __HIP_MEMORY_SCOPE_AGENT);
  }
  if (threadIdx.x == 0) {
    while (__hip_atomic_load(flag, __ATOMIC_RELAXED, __HIP_MEMORY_SCOPE_AGENT) < epoch)
      __builtin_amdgcn_s_sleep(1);
    __threadfence();  // acquire: invalidate stale L1 before reading peers' data
  }
  __syncthreads();
}

__global__ __launch_bounds__(512, 1) void lstm_all(Params P) {
  __shared__ union {
    struct { float gate[8][16][64]; float c[4][64]; } l;   // 33 KB
    struct { float enc[64 * 256]; float dec[64 * NCAT]; float kl[64]; } h; // 69 KB
  } sh;

  const int tid  = threadIdx.x;
  const int lane = tid & 63;
  const int wave = __builtin_amdgcn_readfirstlane((int)(threadIdx.x >> 6)); // force SGPR
  const int blk  = blockIdx.x;
  const int inst = blk >> 6;        // 0..3
  const int wg   = blk & 63;        // 0..63
  const int m0   = wg << 2;         // this WG owns m = m0..m0+3
  const int lstm = inst & 1;        // barrier group id
  const int layer = inst >> 1;

  unsigned* cw   = (unsigned*)(P.ws + 131072);
  unsigned* arr  = cw + lstm * 4096;
  unsigned* flag = arr + 2048;
  const int gb   = (blk & 63) | ((blk >> 7) << 6);   // 0..127 within group
  const bool master = (gb == 0);

  // zero this group's h buffers (group-aligned so visibility stays within the group)
  {
    const int i  = gb * 512 + tid;                      // 0..65535
    const int region = i >> 14;                         // 0..3
    const int off = i & 16383;
    const int rbase = region * 32768;                   // h0b buf0/buf1, h1b buf0/buf1
    P.ws[rbase + lstm * 16384 + off] = 0.f;
  }
  if (tid < 256) sh.l.c[tid >> 6][tid & 63] = 0.f;

  const float* __restrict__ W0 = P.W[inst][0];
  const float* __restrict__ W1 = P.W[inst][1];
  const int part = wave >> 2;          // 0: input-part, 1: hidden-part
  const int kloc = (wave & 3) << 6;    // 0,64,128,192 within the part
  const float* __restrict__ Wp = part ? W1 : W0;
  const int* __restrict__ idxp = lstm ? P.ivo : P.ivu;

  float* h0b = P.ws;            // [buf][lstm][k][b]
  float* h1b = P.ws + 65536;

  group_barrier(arr, flag, 1u, gb, master);   // zero-init visible to whole group

  for (int t = 0; t <= S_LEN; ++t) {
    const bool active = (layer == 0) ? (t < S_LEN) : (t >= 1);
    if (active) {
      const int cur = t & 1, prv = (t + 1) & 1;
      float acc[16];
      #pragma unroll
      for (int jj = 0; jj < 16; ++jj) acc[jj] = 0.f;

      if (layer == 0 && part == 0) {
        // gather path: emb_t[k][b] = VE[idx[b][t]][k]; per-lane contiguous rows
        const int row = idxp[lane * S_LEN + t];
        const float* __restrict__ vr = P.VE + (size_t)row * EMB + kloc;
        #pragma unroll
        for (int kk = 0; kk < 64; kk += 8) {
          float4 a0 = *(const float4*)(vr + kk);
          float4 a1 = *(const float4*)(vr + kk + 4);
          #pragma unroll
          for (int jj = 0; jj < 16; ++jj) {
            const float* __restrict__ wr =
                Wp + (size_t)((jj >> 2) * HID + m0 + (jj & 3)) * 256 + kloc + kk;
            float4 w0 = *(const float4*)(wr);
            float4 w1 = *(const float4*)(wr + 4);
            float s = acc[jj];
            s = fmaf(a0.x, w0.x, s); s = fmaf(a0.y, w0.y, s);
            s = fmaf(a0.z, w0.z, s); s = fmaf(a0.w, w0.w, s);
            s = fmaf(a1.x, w1.x, s); s = fmaf(a1.y, w1.y, s);
            s = fmaf(a1.z, w1.z, s); s = fmaf(a1.w, w1.w, s);
            acc[jj] = s;
          }
        }
      } else {
        // transposed-buffer path: in[k][b], coalesced per k
        const float* inT;
        if (layer == 0)      inT = h0b + prv * 32768 + lstm * 16384;          // h0_{t-1}
        else if (part == 0)  inT = h0b + prv * 32768 + lstm * 16384;          // y0_{t-1}
        else                 inT = h1b + cur * 32768 + lstm * 16384;          // h1_{t-2}
        const float* __restrict__ ip = inT + kloc * 64 + lane;
        #pragma unroll
        for (int kk = 0; kk < 64; kk += 8) {
          float x[8];
          #pragma unroll
          for (int i = 0; i < 8; ++i) x[i] = ip[(kk + i) * 64];
          #pragma unroll
          for (int jj = 0; jj < 16; ++jj) {
            const float* __restrict__ wr =
                Wp + (size_t)((jj >> 2) * HID + m0 + (jj & 3)) * 256 + kloc + kk;
            float4 w0 = *(const float4*)(wr);
            float4 w1 = *(const float4*)(wr + 4);
            float s = acc[jj];
            s = fmaf(x[0], w0.x, s); s = fmaf(x[1], w0.y, s);
            s = fmaf(x[2], w0.z, s); s = fmaf(x[3], w0.w, s);
            s = fmaf(x[4], w1.x, s); s = fmaf(x[5], w1.y, s);
            s = fmaf(x[6], w1.z, s); s = fmaf(x[7], w1.w, s);
            acc[jj] = s;
          }
        }
      }

      #pragma unroll
      for (int jj = 0; jj < 16; ++jj) sh.l.gate[wave][jj][lane] = acc[jj];
      __syncthreads();

      if (tid < 256) {
        const int mi = tid >> 6, b = tid & 63, m = m0 + mi;
        float g4[4];
        #pragma unroll
        for (int g = 0; g < 4; ++g) {
          float s = P.b0[inst][g * HID + m] + P.b1[inst][g * HID + m];
          #pragma unroll
          for (int wv = 0; wv < 8; ++wv) s += sh.l.gate[wv][g * 4 + mi][b];
          g4[g] = s;
        }
        const float ig = 1.f / (1.f + __expf(-g4[0]));
        const float fg = 1.f / (1.f + __expf(-g4[1]));
        const float gg = tanhf(g4[2]);
        const float og = 1.f / (1.f + __expf(-g4[3]));
        const float c  = fg * sh.l.c[mi][b] + ig * gg;
        sh.l.c[mi][b] = c;
        const float hv = og * tanhf(c);
        // layer0 writes h0buf[t&1]; layer1 (step s=t-1) writes h1buf[s&1]=(t+1)&1
        float* hout = (layer == 0 ? h0b + (t & 1) * 32768
                                  : h1b + ((t + 1) & 1) * 32768) + lstm * 16384;
        hout[m * 64 + b] = hv;
      }
    }
    group_barrier(arr, flag, (unsigned)(t + 2), gb, master);
  }

  // ---- head: WG0 only (vu group); must also wait for vo group's final epoch ----
  if (blk == 0) {
    if (tid == 0) {
      unsigned* flag_vo = cw + 4096 + 2048;
      while (__hip_atomic_load(flag_vo, __ATOMIC_RELAXED, __HIP_MEMORY_SCOPE_AGENT) < (unsigned)(S_LEN + 2))
        __builtin_amdgcn_s_sleep(1);
      __threadfence();
    }
    __syncthreads();

    const float* __restrict__ hvu = h1b + 32768;           // h1 final (buf 1), lstm vu
    const float* __restrict__ hvo = h1b + 32768 + 16384;   // lstm vo
    for (int i = tid; i < 64 * 256; i += 512) {
      const int b = i >> 8, m = i & 255;
      float s = P.rob[m];
      for (int j = 0; j < NCAT; ++j) s = fmaf(P.lro[b * NCAT + j], P.roW[m * NCAT + j], s);
      sh.h.enc[i] = fmaxf(s, 0.f);
    }
    __syncthreads();
    for (int i = tid; i < 64 * NCAT; i += 512) {
      const int b = i / NCAT, n = i - b * NCAT;
      const float* __restrict__ wr = P.ruW + n * 768;
      float s = P.rub[n];
      for (int k = 0; k < 256; ++k) s = fmaf(hvu[k * 64 + b], wr[k], s);
      for (int k = 0; k < 256; ++k) s = fmaf(hvo[k * 64 + b], wr[256 + k], s);
      const float* __restrict__ eb = sh.h.enc + b * 256;
      for (int k = 0; k < 256; ++k) s = fmaf(eb[k], wr[512 + k], s);
      sh.h.dec[i] = s;
    }
    __syncthreads();
    if (tid < 64) {
      const int b = tid;
      const float* db = sh.h.dec + b * NCAT;
      float M = db[0];
      for (int j = 1; j < NCAT; ++j) M = fmaxf(M, db[j]);
      float Ssum = 0.f;
      for (int j = 0; j < NCAT; ++j) Ssum += expf(db[j] - M);
      const float lse = M + logf(Ssum);
      float neg = 0.f, kl = 0.f;
      for (int j = 0; j < NCAT; ++j) {
        const float lp = db[j] - lse;
        const float q  = P.lru[b * NCAT + j];
        neg -= q * lp;
        kl  += q * (logf(q) - lp);
      }
      P.out[b] = neg;
      sh.h.kl[b] = kl * 1.4426950408889634f;  // ln -> log2
    }
    __syncthreads();
    if (tid == 0) {
      float s = 0.f;
      for (int b = 0; b < 64; ++b) s += sh.h.kl[b];
      P.out[64] = s * (1.f / 64.f);
    }
  }
}

extern "C" void kernel_launch(void* const* d_in, const int* in_sizes, int n_in,
                              void* d_out, int out_size, void* d_ws, size_t ws_size,
                              hipStream_t stream) {
  Params P;
  P.ivu = (const int*)d_in[0];
  P.ivo = (const int*)d_in[1];
  P.lro = (const float*)d_in[2];
  if (in_sizes[3] >= in_sizes[4]) { P.VE = (const float*)d_in[3]; P.lru = (const float*)d_in[4]; }
  else                            { P.VE = (const float*)d_in[4]; P.lru = (const float*)d_in[3]; }
  // inst: 0 = vu-L0, 1 = vo-L0, 2 = vu-L1, 3 = vo-L1
  P.W[0][0] = (const float*)d_in[5];  P.W[0][1] = (const float*)d_in[6];
  P.b0[0]   = (const float*)d_in[7];  P.b1[0]   = (const float*)d_in[8];
  P.W[2][0] = (const float*)d_in[9];  P.W[2][1] = (const float*)d_in[10];
  P.b0[2]   = (const float*)d_in[11]; P.b1[2]   = (const float*)d_in[12];
  P.W[1][0] = (const float*)d_in[13]; P.W[1][1] = (const float*)d_in[14];
  P.b0[1]   = (const float*)d_in[15]; P.b1[1]   = (const float*)d_in[16];
  P.W[3][0] = (const float*)d_in[17]; P.W[3][1] = (const float*)d_in[18];
  P.b0[3]   = (const float*)d_in[19]; P.b1[3]   = (const float*)d_in[20];
  P.roW = (const float*)d_in[21]; P.rob = (const float*)d_in[22];
  P.ruW = (const float*)d_in[23]; P.rub = (const float*)d_in[24];
  P.ws  = (float*)d_ws;
  P.out = (float*)d_out;

  unsigned* cw = (unsigned*)((float*)d_ws + 131072);
  init_counters<<<32, 256, 0, stream>>>(cw);

  void* args[] = { &P };
  hipLaunchCooperativeKernel((void*)lstm_all, dim3(256), dim3(512), args, 0, stream);
}

// Round 4
// 3419.707 us; speedup vs baseline: 2.5759x; 1.0160x over previous
//
#include <hip/hip_runtime.h>
#include <math.h>

#define S_LEN 100
#define NCAT  18

// ws layout (floats):
//   h0buf: [2 buf][2 lstm][256 k][64 b]  at 0      (65536 floats)
//   h1buf: same                          at 65536  (65536 floats)
// barrier dwords at offset 131072: per group g in {0,1}:
//   arr = cw + g*2048 (256 slots x 4 dwords, 16B padded), flag = arr + 1024
// total = 131072*4 + 4096*4 = 540672 B (<= 557056 proven in R3)

struct Params {
  const int* ivu; const int* ivo;
  const float* lro; const float* lru;
  const float* VE;
  const float* W[4][2];   // [inst][part]; inst: bit0=lstm, bit1=layer; part0=Wih, part1=Whh
  const float* b0[4]; const float* b1[4];
  const float* roW; const float* rob;
  const float* ruW; const float* rub;
  float* ws; float* out;
};

__global__ void init_counters(unsigned* p) {
  p[blockIdx.x * 256 + threadIdx.x] = 0u;   // 16*256 = 4096 dwords
}

// flag-array barrier over 256 WGs; arrival = release store to own 16B slot;
// master wave polls all slots, sets release flag; workers poll flag.
__device__ __forceinline__ void group_barrier(unsigned* arr, unsigned* flag,
                                              unsigned epoch, int gb, bool master) {
  __syncthreads();
  if (threadIdx.x == 0) {
    __threadfence();  // release: drain this WG's global stores
    __hip_atomic_store(arr + gb * 4, epoch, __ATOMIC_RELEASE, __HIP_MEMORY_SCOPE_AGENT);
  }
  if (master && threadIdx.x < 64) {
    unsigned* s0 = arr + (threadIdx.x      ) * 4;
    unsigned* s1 = arr + (threadIdx.x +  64) * 4;
    unsigned* s2 = arr + (threadIdx.x + 128) * 4;
    unsigned* s3 = arr + (threadIdx.x + 192) * 4;
    for (;;) {
      unsigned a = __hip_atomic_load(s0, __ATOMIC_RELAXED, __HIP_MEMORY_SCOPE_AGENT);
      unsigned b = __hip_atomic_load(s1, __ATOMIC_RELAXED, __HIP_MEMORY_SCOPE_AGENT);
      unsigned c = __hip_atomic_load(s2, __ATOMIC_RELAXED, __HIP_MEMORY_SCOPE_AGENT);
      unsigned d = __hip_atomic_load(s3, __ATOMIC_RELAXED, __HIP_MEMORY_SCOPE_AGENT);
      if (__all(a >= epoch && b >= epoch && c >= epoch && d >= epoch)) break;
      __builtin_amdgcn_s_sleep(1);
    }
    if (threadIdx.x == 0)
      __hip_atomic_store(flag, epoch, __ATOMIC_RELEASE, __HIP_MEMORY_SCOPE_AGENT);
  }
  if (threadIdx.x == 0) {
    while (__hip_atomic_load(flag, __ATOMIC_RELAXED, __HIP_MEMORY_SCOPE_AGENT) < epoch)
      __builtin_amdgcn_s_sleep(1);
    __threadfence();  // acquire
  }
  __syncthreads();
}

// 512 WGs x 512 thr, 2 WGs/CU. WG owns 2 h-units (m = 2*wg, 2*wg+1) x 4 gates
// = 8 gate-rows, full K=512. Wave w (0..7) covers k-slice [w*64, w*64+64).
__global__ __launch_bounds__(512, 4) void lstm_all(Params P) {
  __shared__ float wlds[8][512];        // 16 KB: weight slice, staged once
  __shared__ float gate[8][8][64];      // 16 KB: per-wave partials
  __shared__ float cst[2][64];          // c-state
  __shared__ float bias[8];

  const int tid  = threadIdx.x;
  const int lane = tid & 63;
  const int wave = __builtin_amdgcn_readfirstlane((int)(threadIdx.x >> 6));
  const int blk  = blockIdx.x;
  const int inst = blk >> 7;        // 0..3: 0=vu-L0 1=vo-L0 2=vu-L1 3=vo-L1
  const int wg   = blk & 127;       // 0..127
  const int lstm = inst & 1;
  const int layer = inst >> 1;
  const int gb   = wg + layer * 128;   // 0..255 within lstm group
  const bool master = (gb == 0);

  unsigned* cw   = (unsigned*)(P.ws + 131072);
  unsigned* arr  = cw + lstm * 2048;
  unsigned* flag = arr + 1024;

  // ---- one-time staging: weights -> LDS (rows r: global row (r>>1)*256 + 2*wg + (r&1))
  {
    const int r  = tid >> 6;             // 0..7
    const int k0 = (tid & 63) * 8;       // 0..504
    const int R  = (r >> 1) * 256 + wg * 2 + (r & 1);
    const float* src = (k0 < 256) ? (P.W[inst][0] + (size_t)R * 256 + k0)
                                  : (P.W[inst][1] + (size_t)R * 256 + (k0 - 256));
    float4 a = *(const float4*)src;
    float4 b = *(const float4*)(src + 4);
    *(float4*)&wlds[r][k0]     = a;
    *(float4*)&wlds[r][k0 + 4] = b;
  }
  if (tid < 8) {
    const int R = (tid >> 1) * 256 + wg * 2 + (tid & 1);
    bias[tid] = P.b0[inst][R] + P.b1[inst][R];
  }
  if (tid < 128) cst[tid >> 6][tid & 63] = 0.f;

  // zero this group's h buffers (65536 floats per lstm; group has 131072 threads)
  {
    const int i = gb * 512 + tid;
    if (i < 65536) {
      const int region = i >> 14;            // h0b buf0/1, h1b buf0/1
      const int off = i & 16383;
      P.ws[region * 32768 + lstm * 16384 + off] = 0.f;
    }
  }

  float* h0b = P.ws;            // [buf][lstm][k=256][b=64]
  float* h1b = P.ws + 65536;

  const int* __restrict__ idxp = lstm ? P.ivo : P.ivu;
  const int part  = wave >> 2;          // 0: input half (k<256), 1: hidden half
  const int kloc  = (wave & 3) << 6;    // offset within the half
  const int kbase = wave << 6;          // offset within wlds row (0..448)

  group_barrier(arr, flag, 1u, gb, master);

  for (int t = 0; t <= S_LEN; ++t) {
    const bool active = (layer == 0) ? (t < S_LEN) : (t >= 1);
    if (active) {
      const int cur = t & 1, prv = (t + 1) & 1;
      float acc[8];
      #pragma unroll
      for (int r = 0; r < 8; ++r) acc[r] = 0.f;

      if (layer == 0 && part == 0) {
        // embedding gather: lane b reads VE[idx[b][t]][kloc..]; per-lane float4
        const int row = idxp[lane * S_LEN + t];
        const float* __restrict__ vr = P.VE + (size_t)row * 256 + kloc;
        #pragma unroll
        for (int kk = 0; kk < 64; kk += 4) {
          float4 x4 = *(const float4*)(vr + kk);
          #pragma unroll
          for (int r = 0; r < 8; ++r) {
            float4 w4 = *(const float4*)&wlds[r][kbase + kk];
            float s = acc[r];
            s = fmaf(x4.x, w4.x, s); s = fmaf(x4.y, w4.y, s);
            s = fmaf(x4.z, w4.z, s); s = fmaf(x4.w, w4.w, s);
            acc[r] = s;
          }
        }
      } else {
        const float* inT;
        if (layer == 0)      inT = h0b + prv * 32768 + lstm * 16384;  // h0_{t-1}
        else if (part == 0)  inT = h0b + prv * 32768 + lstm * 16384;  // y0_{t-1}
        else                 inT = h1b + cur * 32768 + lstm * 16384;  // h1_{t-2}
        const float* __restrict__ ip = inT + kloc * 64 + lane;
        #pragma unroll
        for (int kk = 0; kk < 64; kk += 4) {
          float x0 = ip[(kk + 0) * 64];
          float x1 = ip[(kk + 1) * 64];
          float x2 = ip[(kk + 2) * 64];
          float x3 = ip[(kk + 3) * 64];
          #pragma unroll
          for (int r = 0; r < 8; ++r) {
            float4 w4 = *(const float4*)&wlds[r][kbase + kk];
            float s = acc[r];
            s = fmaf(x0, w4.x, s); s = fmaf(x1, w4.y, s);
            s = fmaf(x2, w4.z, s); s = fmaf(x3, w4.w, s);
            acc[r] = s;
          }
        }
      }

      #pragma unroll
      for (int r = 0; r < 8; ++r) gate[wave][r][lane] = acc[r];
      __syncthreads();

      if (tid < 128) {
        const int jl = tid >> 6, b = tid & 63;   // jl: 0..1 local m
        float g4[4];
        #pragma unroll
        for (int g = 0; g < 4; ++g) {
          const int r = g * 2 + jl;
          float s = bias[r];
          #pragma unroll
          for (int w = 0; w < 8; ++w) s += gate[w][r][b];
          g4[g] = s;
        }
        const float ig = 1.f / (1.f + __expf(-g4[0]));
        const float fg = 1.f / (1.f + __expf(-g4[1]));
        const float gg = tanhf(g4[2]);
        const float og = 1.f / (1.f + __expf(-g4[3]));
        const float c  = fg * cst[jl][b] + ig * gg;
        cst[jl][b] = c;
        const float hv = og * tanhf(c);
        const int m = wg * 2 + jl;
        float* hout = (layer == 0 ? h0b + cur * 32768
                                  : h1b + prv * 32768) + lstm * 16384;
        hout[m * 64 + b] = hv;
      }
    }
    if (t < S_LEN) group_barrier(arr, flag, (unsigned)(t + 2), gb, master);
  }
}

__global__ __launch_bounds__(512) void head_kernel(Params P) {
  __shared__ float enc[64 * 256];
  __shared__ float dec[64 * NCAT];
  __shared__ float kl[64];
  const int tid = threadIdx.x;
  const float* __restrict__ hvu = P.ws + 65536 + 32768;          // h1 final (buf 1), vu
  const float* __restrict__ hvo = hvu + 16384;                   // vo

  for (int i = tid; i < 64 * 256; i += 512) {
    const int b = i >> 8, m = i & 255;
    float s = P.rob[m];
    for (int j = 0; j < NCAT; ++j) s = fmaf(P.lro[b * NCAT + j], P.roW[m * NCAT + j], s);
    enc[i] = fmaxf(s, 0.f);
  }
  __syncthreads();
  for (int i = tid; i < 64 * NCAT; i += 512) {
    const int b = i / NCAT, n = i - b * NCAT;
    const float* __restrict__ wr = P.ruW + n * 768;
    float s = P.rub[n];
    for (int k = 0; k < 256; ++k) s = fmaf(hvu[k * 64 + b], wr[k], s);
    for (int k = 0; k < 256; ++k) s = fmaf(hvo[k * 64 + b], wr[256 + k], s);
    const float* __restrict__ eb = enc + b * 256;
    for (int k = 0; k < 256; ++k) s = fmaf(eb[k], wr[512 + k], s);
    dec[i] = s;
  }
  __syncthreads();
  if (tid < 64) {
    const int b = tid;
    const float* db = dec + b * NCAT;
    float M = db[0];
    for (int j = 1; j < NCAT; ++j) M = fmaxf(M, db[j]);
    float Ssum = 0.f;
    for (int j = 0; j < NCAT; ++j) Ssum += expf(db[j] - M);
    const float lse = M + logf(Ssum);
    float neg = 0.f, k2 = 0.f;
    for (int j = 0; j < NCAT; ++j) {
      const float lp = db[j] - lse;
      const float q  = P.lru[b * NCAT + j];
      neg -= q * lp;
      k2  += q * (logf(q) - lp);
    }
    P.out[b] = neg;
    kl[b] = k2 * 1.4426950408889634f;  // ln -> log2
  }
  __syncthreads();
  if (tid == 0) {
    float s = 0.f;
    for (int b = 0; b < 64; ++b) s += kl[b];
    P.out[64] = s * (1.f / 64.f);
  }
}

extern "C" void kernel_launch(void* const* d_in, const int* in_sizes, int n_in,
                              void* d_out, int out_size, void* d_ws, size_t ws_size,
                              hipStream_t stream) {
  Params P;
  P.ivu = (const int*)d_in[0];
  P.ivo = (const int*)d_in[1];
  P.lro = (const float*)d_in[2];
  if (in_sizes[3] >= in_sizes[4]) { P.VE = (const float*)d_in[3]; P.lru = (const float*)d_in[4]; }
  else                            { P.VE = (const float*)d_in[4]; P.lru = (const float*)d_in[3]; }
  // inst: 0 = vu-L0, 1 = vo-L0, 2 = vu-L1, 3 = vo-L1
  P.W[0][0] = (const float*)d_in[5];  P.W[0][1] = (const float*)d_in[6];
  P.b0[0]   = (const float*)d_in[7];  P.b1[0]   = (const float*)d_in[8];
  P.W[2][0] = (const float*)d_in[9];  P.W[2][1] = (const float*)d_in[10];
  P.b0[2]   = (const float*)d_in[11]; P.b1[2]   = (const float*)d_in[12];
  P.W[1][0] = (const float*)d_in[13]; P.W[1][1] = (const float*)d_in[14];
  P.b0[1]   = (const float*)d_in[15]; P.b1[1]   = (const float*)d_in[16];
  P.W[3][0] = (const float*)d_in[17]; P.W[3][1] = (const float*)d_in[18];
  P.b0[3]   = (const float*)d_in[19]; P.b1[3]   = (const float*)d_in[20];
  P.roW = (const float*)d_in[21]; P.rob = (const float*)d_in[22];
  P.ruW = (const float*)d_in[23]; P.rub = (const float*)d_in[24];
  P.ws  = (float*)d_ws;
  P.out = (float*)d_out;

  unsigned* cw = (unsigned*)((float*)d_ws + 131072);
  init_counters<<<16, 256, 0, stream>>>(cw);

  void* args[] = { &P };
  hipLaunchCooperativeKernel((void*)lstm_all, dim3(512), dim3(512), args, 0, stream);
  head_kernel<<<1, 512, 0, stream>>>(P);
}

// Round 5
// 1168.643 us; speedup vs baseline: 7.5376x; 2.9262x over previous
//
#include <hip/hip_runtime.h>
#include <math.h>

#define S_LEN 100
#define NCAT  18

#define AT_LOAD(p)     __hip_atomic_load((p), __ATOMIC_RELAXED, __HIP_MEMORY_SCOPE_AGENT)
#define AT_STORE(p, v) __hip_atomic_store((p), (v), __ATOMIC_RELAXED, __HIP_MEMORY_SCOPE_AGENT)

// ws layout (floats):
//   h0buf: [2 buf][2 lstm][256 k][64 b]  at 0      (65536 floats)
//   h1buf: same                          at 65536  (65536 floats)
// barrier dwords at offset 131072: per group g in {0,1}:
//   arr = cw + g*2048 (256 slots x 4 dwords, 16B padded), flag = arr + 1024
// All h + barrier accesses are relaxed agent-scope atomics (sc1, IF-coherent)
// => NO __threadfence (avoids buffer_wbl2/buffer_inv L2 flush storms).

struct Params {
  const int* ivu; const int* ivo;
  const float* lro; const float* lru;
  const float* VE;
  const float* W[4][2];   // [inst][part]; inst: bit0=lstm, bit1=layer; part0=Wih, part1=Whh
  const float* b0[4]; const float* b1[4];
  const float* roW; const float* rob;
  const float* ruW; const float* rub;
  float* ws; float* out;
};

__global__ void init_counters(unsigned* p) {
  p[blockIdx.x * 256 + threadIdx.x] = 0u;   // 16*256 = 4096 dwords
}

// flag-array barrier over 256 WGs; NO fences. __syncthreads() drains vmcnt(0)
// for every wave (compiler-emitted before s_barrier), so all h stores (sc1,
// IF-visible) complete before the arrival store issues.
__device__ __forceinline__ void group_barrier(unsigned* arr, unsigned* flag,
                                              unsigned epoch, int gb, bool master) {
  __syncthreads();
  if (threadIdx.x == 0) {
    AT_STORE(arr + gb * 4, epoch);
  }
  if (master && threadIdx.x < 64) {
    unsigned* s0 = arr + (threadIdx.x      ) * 4;
    unsigned* s1 = arr + (threadIdx.x +  64) * 4;
    unsigned* s2 = arr + (threadIdx.x + 128) * 4;
    unsigned* s3 = arr + (threadIdx.x + 192) * 4;
    for (;;) {
      unsigned a = AT_LOAD(s0);
      unsigned b = AT_LOAD(s1);
      unsigned c = AT_LOAD(s2);
      unsigned d = AT_LOAD(s3);
      if (__all(a >= epoch && b >= epoch && c >= epoch && d >= epoch)) break;
      __builtin_amdgcn_s_sleep(1);
    }
    if (threadIdx.x == 0) AT_STORE(flag, epoch);
  }
  if (threadIdx.x == 0) {
    while (AT_LOAD(flag) < epoch) __builtin_amdgcn_s_sleep(1);
  }
  __syncthreads();
}

// 512 WGs x 512 thr, 2 WGs/CU. WG owns 2 h-units (m = 2*wg, 2*wg+1) x 4 gates
// = 8 gate-rows, full K=512. Wave w (0..7) covers k-slice [w*64, w*64+64).
__global__ __launch_bounds__(512, 4) void lstm_all(Params P) {
  __shared__ float wlds[8][512];        // 16 KB: weight slice, staged once
  __shared__ float gate[8][8][64];      // 16 KB: per-wave partials
  __shared__ float cst[2][64];          // c-state
  __shared__ float bias[8];

  const int tid  = threadIdx.x;
  const int lane = tid & 63;
  const int wave = __builtin_amdgcn_readfirstlane((int)(threadIdx.x >> 6));
  const int blk  = blockIdx.x;
  const int inst = blk >> 7;        // 0..3: 0=vu-L0 1=vo-L0 2=vu-L1 3=vo-L1
  const int wg   = blk & 127;       // 0..127
  const int lstm = inst & 1;
  const int layer = inst >> 1;
  const int gb   = wg + layer * 128;   // 0..255 within lstm group
  const bool master = (gb == 0);

  unsigned* cw   = (unsigned*)(P.ws + 131072);
  unsigned* arr  = cw + lstm * 2048;
  unsigned* flag = arr + 1024;

  // ---- one-time staging: weights -> LDS (rows r: global row (r>>1)*256 + 2*wg + (r&1))
  {
    const int r  = tid >> 6;             // 0..7
    const int k0 = (tid & 63) * 8;       // 0..504
    const int R  = (r >> 1) * 256 + wg * 2 + (r & 1);
    const float* src = (k0 < 256) ? (P.W[inst][0] + (size_t)R * 256 + k0)
                                  : (P.W[inst][1] + (size_t)R * 256 + (k0 - 256));
    float4 a = *(const float4*)src;
    float4 b = *(const float4*)(src + 4);
    *(float4*)&wlds[r][k0]     = a;
    *(float4*)&wlds[r][k0 + 4] = b;
  }
  if (tid < 8) {
    const int R = (tid >> 1) * 256 + wg * 2 + (tid & 1);
    bias[tid] = P.b0[inst][R] + P.b1[inst][R];
  }
  if (tid < 128) cst[tid >> 6][tid & 63] = 0.f;

  // zero this group's h buffers via sc1 stores (readers use sc1 loads)
  {
    const int i = gb * 512 + tid;
    if (i < 65536) {
      const int region = i >> 14;            // h0b buf0/1, h1b buf0/1
      const int off = i & 16383;
      AT_STORE(&P.ws[region * 32768 + lstm * 16384 + off], 0.f);
    }
  }

  float* h0b = P.ws;            // [buf][lstm][k=256][b=64]
  float* h1b = P.ws + 65536;

  const int* __restrict__ idxp = lstm ? P.ivo : P.ivu;
  const int part  = wave >> 2;          // 0: input half (k<256), 1: hidden half
  const int kloc  = (wave & 3) << 6;    // offset within the half
  const int kbase = wave << 6;          // offset within wlds row (0..448)

  group_barrier(arr, flag, 1u, gb, master);

  for (int t = 0; t <= S_LEN; ++t) {
    const bool active = (layer == 0) ? (t < S_LEN) : (t >= 1);
    if (active) {
      const int cur = t & 1, prv = (t + 1) & 1;
      float acc[8];
      #pragma unroll
      for (int r = 0; r < 8; ++r) acc[r] = 0.f;

      if (layer == 0 && part == 0) {
        // embedding gather: lane b reads VE[idx[b][t]][kloc..]; read-only => cached loads
        const int row = idxp[lane * S_LEN + t];
        const float* __restrict__ vr = P.VE + (size_t)row * 256 + kloc;
        #pragma unroll
        for (int kk = 0; kk < 64; kk += 4) {
          float4 x4 = *(const float4*)(vr + kk);
          #pragma unroll
          for (int r = 0; r < 8; ++r) {
            float4 w4 = *(const float4*)&wlds[r][kbase + kk];
            float s = acc[r];
            s = fmaf(x4.x, w4.x, s); s = fmaf(x4.y, w4.y, s);
            s = fmaf(x4.z, w4.z, s); s = fmaf(x4.w, w4.w, s);
            acc[r] = s;
          }
        }
      } else {
        const float* inT;
        if (layer == 0)      inT = h0b + prv * 32768 + lstm * 16384;  // h0_{t-1}
        else if (part == 0)  inT = h0b + prv * 32768 + lstm * 16384;  // y0_{t-1}
        else                 inT = h1b + cur * 32768 + lstm * 16384;  // h1_{t-2}
        const float* __restrict__ ip = inT + kloc * 64 + lane;
        #pragma unroll
        for (int kk = 0; kk < 64; kk += 4) {
          float x0 = AT_LOAD(ip + (kk + 0) * 64);
          float x1 = AT_LOAD(ip + (kk + 1) * 64);
          float x2 = AT_LOAD(ip + (kk + 2) * 64);
          float x3 = AT_LOAD(ip + (kk + 3) * 64);
          #pragma unroll
          for (int r = 0; r < 8; ++r) {
            float4 w4 = *(const float4*)&wlds[r][kbase + kk];
            float s = acc[r];
            s = fmaf(x0, w4.x, s); s = fmaf(x1, w4.y, s);
            s = fmaf(x2, w4.z, s); s = fmaf(x3, w4.w, s);
            acc[r] = s;
          }
        }
      }

      #pragma unroll
      for (int r = 0; r < 8; ++r) gate[wave][r][lane] = acc[r];
      __syncthreads();

      if (tid < 128) {
        const int jl = tid >> 6, b = tid & 63;   // jl: 0..1 local m
        float g4[4];
        #pragma unroll
        for (int g = 0; g < 4; ++g) {
          const int r = g * 2 + jl;
          float s = bias[r];
          #pragma unroll
          for (int w = 0; w < 8; ++w) s += gate[w][r][b];
          g4[g] = s;
        }
        const float ig = 1.f / (1.f + __expf(-g4[0]));
        const float fg = 1.f / (1.f + __expf(-g4[1]));
        const float gg = tanhf(g4[2]);
        const float og = 1.f / (1.f + __expf(-g4[3]));
        const float c  = fg * cst[jl][b] + ig * gg;
        cst[jl][b] = c;
        const float hv = og * tanhf(c);
        const int m = wg * 2 + jl;
        float* hout = (layer == 0 ? h0b + cur * 32768
                                  : h1b + prv * 32768) + lstm * 16384;
        AT_STORE(&hout[m * 64 + b], hv);
      }
    }
    if (t < S_LEN) group_barrier(arr, flag, (unsigned)(t + 2), gb, master);
  }
}

__global__ __launch_bounds__(512) void head_kernel(Params P) {
  __shared__ float enc[64 * 256];
  __shared__ float dec[64 * NCAT];
  __shared__ float kl[64];
  const int tid = threadIdx.x;
  const float* __restrict__ hvu = P.ws + 65536 + 32768;          // h1 final (buf 1), vu
  const float* __restrict__ hvo = hvu + 16384;                   // vo

  for (int i = tid; i < 64 * 256; i += 512) {
    const int b = i >> 8, m = i & 255;
    float s = P.rob[m];
    for (int j = 0; j < NCAT; ++j) s = fmaf(P.lro[b * NCAT + j], P.roW[m * NCAT + j], s);
    enc[i] = fmaxf(s, 0.f);
  }
  __syncthreads();
  for (int i = tid; i < 64 * NCAT; i += 512) {
    const int b = i / NCAT, n = i - b * NCAT;
    const float* __restrict__ wr = P.ruW + n * 768;
    float s = P.rub[n];
    for (int k = 0; k < 256; ++k) s = fmaf(hvu[k * 64 + b], wr[k], s);
    for (int k = 0; k < 256; ++k) s = fmaf(hvo[k * 64 + b], wr[256 + k], s);
    const float* __restrict__ eb = enc + b * 256;
    for (int k = 0; k < 256; ++k) s = fmaf(eb[k], wr[512 + k], s);
    dec[i] = s;
  }
  __syncthreads();
  if (tid < 64) {
    const int b = tid;
    const float* db = dec + b * NCAT;
    float M = db[0];
    for (int j = 1; j < NCAT; ++j) M = fmaxf(M, db[j]);
    float Ssum = 0.f;
    for (int j = 0; j < NCAT; ++j) Ssum += expf(db[j] - M);
    const float lse = M + logf(Ssum);
    float neg = 0.f, k2 = 0.f;
    for (int j = 0; j < NCAT; ++j) {
      const float lp = db[j] - lse;
      const float q  = P.lru[b * NCAT + j];
      neg -= q * lp;
      k2  += q * (logf(q) - lp);
    }
    P.out[b] = neg;
    kl[b] = k2 * 1.4426950408889634f;  // ln -> log2
  }
  __syncthreads();
  if (tid == 0) {
    float s = 0.f;
    for (int b = 0; b < 64; ++b) s += kl[b];
    P.out[64] = s * (1.f / 64.f);
  }
}

extern "C" void kernel_launch(void* const* d_in, const int* in_sizes, int n_in,
                              void* d_out, int out_size, void* d_ws, size_t ws_size,
                              hipStream_t stream) {
  Params P;
  P.ivu = (const int*)d_in[0];
  P.ivo = (const int*)d_in[1];
  P.lro = (const float*)d_in[2];
  if (in_sizes[3] >= in_sizes[4]) { P.VE = (const float*)d_in[3]; P.lru = (const float*)d_in[4]; }
  else                            { P.VE = (const float*)d_in[4]; P.lru = (const float*)d_in[3]; }
  // inst: 0 = vu-L0, 1 = vo-L0, 2 = vu-L1, 3 = vo-L1
  P.W[0][0] = (const float*)d_in[5];  P.W[0][1] = (const float*)d_in[6];
  P.b0[0]   = (const float*)d_in[7];  P.b1[0]   = (const float*)d_in[8];
  P.W[2][0] = (const float*)d_in[9];  P.W[2][1] = (const float*)d_in[10];
  P.b0[2]   = (const float*)d_in[11]; P.b1[2]   = (const float*)d_in[12];
  P.W[1][0] = (const float*)d_in[13]; P.W[1][1] = (const float*)d_in[14];
  P.b0[1]   = (const float*)d_in[15]; P.b1[1]   = (const float*)d_in[16];
  P.W[3][0] = (const float*)d_in[17]; P.W[3][1] = (const float*)d_in[18];
  P.b0[3]   = (const float*)d_in[19]; P.b1[3]   = (const float*)d_in[20];
  P.roW = (const float*)d_in[21]; P.rob = (const float*)d_in[22];
  P.ruW = (const float*)d_in[23]; P.rub = (const float*)d_in[24];
  P.ws  = (float*)d_ws;
  P.out = (float*)d_out;

  unsigned* cw = (unsigned*)((float*)d_ws + 131072);
  init_counters<<<16, 256, 0, stream>>>(cw);

  void* args[] = { &P };
  hipLaunchCooperativeKernel((void*)lstm_all, dim3(512), dim3(512), args, 0, stream);
  head_kernel<<<1, 512, 0, stream>>>(P);
}